// Round 7
// baseline (90.173 us; speedup 1.0000x reference)
//
#include <hip/hip_runtime.h>
#include <math.h>

#define NN 1024
#define MM 1024
#define DD 256
#define TILE 64
#define NTB 16
#define PITCH 260  // 256 + 4 pad: conflict-free b128 reads (proven R1/R4)
#define REP 3      // MEASUREMENT ROUND: 3x compute to force kernels into rocprof top-5

__device__ inline void merge_ms(float& m, float& s, float m2, float s2) {
  float mn = fmaxf(m, m2);
  s = s * __expf(m - mn) + s2 * __expf(m2 - mn);
  m = mn;
}

__device__ inline float wredSum(float v) {
#pragma unroll
  for (int o = 32; o > 0; o >>= 1) v += __shfl_down(v, o, 64);
  return v;
}

// ---------------- K1: distance tile + S store + row/col softmax partials ----
__global__ __launch_bounds__(256) void k_tile(const float* __restrict__ zx,
                                              const float* __restrict__ zy,
                                              float* __restrict__ S,
                                              float* __restrict__ rowPM,
                                              float* __restrict__ rowPS,
                                              float* __restrict__ colPM,
                                              float* __restrict__ colPS,
                                              int* __restrict__ counter) {
  __shared__ float xs[TILE * PITCH];
  __shared__ float ys[TILE * PITCH];
  const int it = blockIdx.y, jt = blockIdx.x;
  const int i0 = it * TILE, j0 = jt * TILE;
  const int t = threadIdx.x;
  const int tx = t & 15, ty = t >> 4;

  if (it == 0 && jt == 0 && t == 0) counter[0] = 0;  // graph-replay-safe reset

#pragma unroll
  for (int k = 0; k < 16; ++k) {
    int idx4 = t + k * 256;
    int r = idx4 >> 6;
    int c4 = idx4 & 63;
    float4 vx = reinterpret_cast<const float4*>(zx + (size_t)(i0 + r) * DD)[c4];
    float4 vy = reinterpret_cast<const float4*>(zy + (size_t)(j0 + r) * DD)[c4];
    *reinterpret_cast<float4*>(&xs[r * PITCH + c4 * 4]) = vx;
    *reinterpret_cast<float4*>(&ys[r * PITCH + c4 * 4]) = vy;
  }
  __syncthreads();

  float acc4[4][4];
  // REP'd compute section: recompute the tile REP times; keep-alives defeat DCE.
  for (int rep = 0; rep < REP; ++rep) {
    float a4[4][4] = {{0.f}};
    for (int d4 = 0; d4 < DD / 4; ++d4) {
      float4 xa[4], yb[4];
#pragma unroll
      for (int a = 0; a < 4; ++a)
        xa[a] = *reinterpret_cast<const float4*>(&xs[(ty + a * 16) * PITCH + d4 * 4]);
#pragma unroll
      for (int b = 0; b < 4; ++b)
        yb[b] = *reinterpret_cast<const float4*>(&ys[(tx + b * 16) * PITCH + d4 * 4]);
#pragma unroll
      for (int a = 0; a < 4; ++a)
#pragma unroll
        for (int b = 0; b < 4; ++b) {
          a4[a][b] += fabsf(xa[a].x - yb[b].x) + fabsf(xa[a].y - yb[b].y) +
                      fabsf(xa[a].z - yb[b].z) + fabsf(xa[a].w - yb[b].w);
        }
    }
#pragma unroll
    for (int a = 0; a < 4; ++a)
#pragma unroll
      for (int b = 0; b < 4; ++b) {
        asm volatile("" : "+v"(a4[a][b]));  // live + opaque across reps
        acc4[a][b] = a4[a][b];
      }
  }

#pragma unroll
  for (int a = 0; a < 4; ++a) {
    int i = i0 + ty + a * 16;
#pragma unroll
    for (int b = 0; b < 4; ++b) {
      int j = j0 + tx + b * 16;
      S[(size_t)i * MM + j] = -acc4[a][b];
    }
  }

  // row partials
#pragma unroll
  for (int a = 0; a < 4; ++a) {
    float m = -acc4[a][0];
#pragma unroll
    for (int b = 1; b < 4; ++b) m = fmaxf(m, -acc4[a][b]);
    float s = 0.f;
#pragma unroll
    for (int b = 0; b < 4; ++b) s += __expf(-acc4[a][b] - m);
#pragma unroll
    for (int off = 1; off < 16; off <<= 1) {
      float m2 = __shfl_xor(m, off, 64);
      float s2 = __shfl_xor(s, off, 64);
      merge_ms(m, s, m2, s2);
    }
    if (tx == 0) {
      int i = i0 + ty + a * 16;
      rowPM[(size_t)jt * NN + i] = m;
      rowPS[(size_t)jt * NN + i] = s;
    }
  }

  // col partials
  __shared__ float lm[16][64];
  __shared__ float lsv[16][64];
#pragma unroll
  for (int b = 0; b < 4; ++b) {
    int c = tx + b * 16;
    float m = -acc4[0][b];
#pragma unroll
    for (int a = 1; a < 4; ++a) m = fmaxf(m, -acc4[a][b]);
    float s = 0.f;
#pragma unroll
    for (int a = 0; a < 4; ++a) s += __expf(-acc4[a][b] - m);
    lm[ty][c] = m;
    lsv[ty][c] = s;
  }
  __syncthreads();
  if (t < 64) {
    float m = lm[0][t], s = lsv[0][t];
#pragma unroll
    for (int k = 1; k < 16; ++k) merge_ms(m, s, lm[k][t], lsv[k][t]);
    colPM[(size_t)it * MM + j0 + t] = m;
    colPS[(size_t)it * MM + j0 + t] = s;
  }
}

// ---------------- K2: merge stats + weighted accumulation + final ----------
__global__ __launch_bounds__(256) void k_wacc(const float* __restrict__ S,
                                              const float* __restrict__ rowPM,
                                              const float* __restrict__ rowPS,
                                              const float* __restrict__ colPM,
                                              const float* __restrict__ colPS,
                                              float* __restrict__ bNum,
                                              float* __restrict__ bDen,
                                              int* __restrict__ counter,
                                              float* __restrict__ out) {
  const int bid = blockIdx.x;  // rows [bid*4, bid*4+4)
  const int t = threadIdx.x;

  // row stats for this block's 4 rows (once; outside REP)
  __shared__ float rowMl[4], rowIl[4];
  if (t < 4) {
    int r = bid * 4 + t;
    float m = rowPM[r], s = rowPS[r];
#pragma unroll
    for (int k = 1; k < NTB; ++k)
      merge_ms(m, s, rowPM[(size_t)k * NN + r], rowPS[(size_t)k * NN + r]);
    rowMl[t] = m;
    rowIl[t] = 1.f / s;
  }
  __syncthreads();

  float num, den;
  // REP'd compute: col-merge + weighted accumulation
  for (int rep = 0; rep < REP; ++rep) {
    float4 cm = reinterpret_cast<const float4*>(colPM)[t];
    float4 cs = reinterpret_cast<const float4*>(colPS)[t];
#pragma unroll
    for (int k = 1; k < NTB; ++k) {
      float4 m2 = reinterpret_cast<const float4*>(colPM + (size_t)k * MM)[t];
      float4 s2 = reinterpret_cast<const float4*>(colPS + (size_t)k * MM)[t];
      merge_ms(cm.x, cs.x, m2.x, s2.x);
      merge_ms(cm.y, cs.y, m2.y, s2.y);
      merge_ms(cm.z, cs.z, m2.z, s2.z);
      merge_ms(cm.w, cs.w, m2.w, s2.w);
    }
    float4 ci;
    ci.x = 1.f / cs.x; ci.y = 1.f / cs.y; ci.z = 1.f / cs.z; ci.w = 1.f / cs.w;

    float n_ = 0.f, d_ = 0.f;
#pragma unroll
    for (int rl = 0; rl < 4; ++rl) {
      int row = bid * 4 + rl;
      float4 v = reinterpret_cast<const float4*>(S + (size_t)row * MM)[t];
      float rm = rowMl[rl], ri = rowIl[rl];
#define DO_COMP(VX, CMX, CIX)                 \
      {                                       \
        float a = __expf((VX) - rm) * ri;     \
        float b = __expf((VX) - (CMX)) * (CIX); \
        float w = a + b - a * b;              \
        n_ += w * (VX);                       \
        d_ += w;                              \
      }
      DO_COMP(v.x, cm.x, ci.x)
      DO_COMP(v.y, cm.y, ci.y)
      DO_COMP(v.z, cm.z, ci.z)
      DO_COMP(v.w, cm.w, ci.w)
#undef DO_COMP
    }
    asm volatile("" : "+v"(n_), "+v"(d_));
    num = n_;
    den = d_;
  }

  // block reduce
  num = wredSum(num);
  den = wredSum(den);
  __shared__ float rn[4], rd[4];
  const int lane = t & 63, wv = t >> 6;
  if (lane == 0) { rn[wv] = num; rd[wv] = den; }
  __syncthreads();
  if (t == 0) {
    bNum[bid] = rn[0] + rn[1] + rn[2] + rn[3];
    bDen[bid] = rd[0] + rd[1] + rd[2] + rd[3];
  }

  // last-block-done final reduction
  __shared__ int isLast;
  if (t == 0) {
    __threadfence();
    int ticket = atomicAdd(counter, 1);
    isLast = (ticket == 255) ? 1 : 0;
  }
  __syncthreads();
  if (isLast) {
    __threadfence();
    float n = bNum[t];
    float d = bDen[t];
    n = wredSum(n);
    d = wredSum(d);
    if (lane == 0) { rn[wv] = n; rd[wv] = d; }
    __syncthreads();
    if (t == 0) out[0] = (rn[0] + rn[1] + rn[2] + rn[3]) / (rd[0] + rd[1] + rd[2] + rd[3]);
  }
}

// ---------------- launch ----------------
extern "C" void kernel_launch(void* const* d_in, const int* in_sizes, int n_in,
                              void* d_out, int out_size, void* d_ws, size_t ws_size,
                              hipStream_t stream) {
  const float* zx = (const float*)d_in[0];
  const float* zy = (const float*)d_in[1];
  float* out = (float*)d_out;

  float* ws = (float*)d_ws;
  float* S     = ws;                        // 1M floats
  float* rowPM = S + (size_t)NN * MM;       // 16K
  float* rowPS = rowPM + NTB * NN;          // 16K
  float* colPM = rowPS + NTB * NN;          // 16K
  float* colPS = colPM + NTB * MM;          // 16K
  float* bNum  = colPS + NTB * MM;          // 256
  float* bDen  = bNum + 256;                // 256
  int*   counter = (int*)(bDen + 256);      // 1

  k_tile<<<dim3(NTB, NTB), 256, 0, stream>>>(zx, zy, S, rowPM, rowPS, colPM, colPS, counter);
  k_wacc<<<256, 256, 0, stream>>>(S, rowPM, rowPS, colPM, colPS, bNum, bDen, counter, out);
}

// Round 8
// 41.815 us; speedup vs baseline: 2.1565x; 2.1565x over previous
//
#include <hip/hip_runtime.h>
#include <math.h>

#define NN 1024
#define MM 1024
#define DD 256
#define TILE 64
#define NTB 16
#define PITCH 260  // 256 + 4 pad: conflict-free b128 reads (proven R1/R4)

__device__ inline void merge_ms(float& m, float& s, float m2, float s2) {
  float mn = fmaxf(m, m2);
  s = s * __expf(m - mn) + s2 * __expf(m2 - mn);
  m = mn;
}

__device__ inline float wredSum(float v) {
#pragma unroll
  for (int o = 32; o > 0; o >>= 1) v += __shfl_down(v, o, 64);
  return v;
}

// ---------------- K1: distance tile, 512 threads, d-split halves ----------
__global__ __launch_bounds__(512) void k_tile(const float* __restrict__ zx,
                                              const float* __restrict__ zy,
                                              float* __restrict__ S,
                                              float* __restrict__ rowPM,
                                              float* __restrict__ rowPS,
                                              float* __restrict__ colPM,
                                              float* __restrict__ colPS,
                                              int* __restrict__ counter) {
  __shared__ float xs[TILE * PITCH];   // 65 KiB
  __shared__ float ys[TILE * PITCH];   // 65 KiB
  __shared__ float ex[16 * 256];       // 16 KiB acc-exchange
  __shared__ float lm[16][64];         // 4 KiB
  __shared__ float lsv[16][64];        // 4 KiB

  const int it = blockIdx.y, jt = blockIdx.x;
  const int i0 = it * TILE, j0 = jt * TILE;
  const int t = threadIdx.x;           // 0..511
  const int tt = t & 255;              // tile-thread id
  const int h = t >> 8;                // d-half: 0 or 1
  const int tx = tt & 15, ty = tt >> 4;

  if (it == 0 && jt == 0 && t == 0) counter[0] = 0;  // graph-replay-safe reset

  // stage 64 rows x 256 floats of both inputs (coalesced float4, 512 threads)
#pragma unroll
  for (int k = 0; k < 8; ++k) {
    int idx4 = t + k * 512;
    int r = idx4 >> 6;
    int c4 = idx4 & 63;
    float4 vx = reinterpret_cast<const float4*>(zx + (size_t)(i0 + r) * DD)[c4];
    float4 vy = reinterpret_cast<const float4*>(zy + (size_t)(j0 + r) * DD)[c4];
    *reinterpret_cast<float4*>(&xs[r * PITCH + c4 * 4]) = vx;
    *reinterpret_cast<float4*>(&ys[r * PITCH + c4 * 4]) = vy;
  }
  __syncthreads();

  // each half accumulates 32 of the 64 d4-steps for the SAME (i,j) 4x4 tile
  float acc4[4][4] = {{0.f}};
  const int d4base = h * 32;
  for (int d4 = d4base; d4 < d4base + 32; ++d4) {
    float4 xa[4], yb[4];
#pragma unroll
    for (int a = 0; a < 4; ++a)
      xa[a] = *reinterpret_cast<const float4*>(&xs[(ty + a * 16) * PITCH + d4 * 4]);
#pragma unroll
    for (int b = 0; b < 4; ++b)
      yb[b] = *reinterpret_cast<const float4*>(&ys[(tx + b * 16) * PITCH + d4 * 4]);
#pragma unroll
    for (int a = 0; a < 4; ++a)
#pragma unroll
      for (int b = 0; b < 4; ++b) {
        acc4[a][b] += fabsf(xa[a].x - yb[b].x) + fabsf(xa[a].y - yb[b].y) +
                      fabsf(xa[a].z - yb[b].z) + fabsf(xa[a].w - yb[b].w);
      }
  }

  // combine halves: h=1 publishes, h=0 adds (lane-consecutive, conflict-free)
  __syncthreads();
  if (h == 1) {
#pragma unroll
    for (int a = 0; a < 4; ++a)
#pragma unroll
      for (int b = 0; b < 4; ++b) ex[(a * 4 + b) * 256 + tt] = acc4[a][b];
  }
  __syncthreads();
  if (h == 0) {
#pragma unroll
    for (int a = 0; a < 4; ++a)
#pragma unroll
      for (int b = 0; b < 4; ++b) acc4[a][b] += ex[(a * 4 + b) * 256 + tt];
  }

  if (h == 0) {
    // store S tile
#pragma unroll
    for (int a = 0; a < 4; ++a) {
      int i = i0 + ty + a * 16;
#pragma unroll
      for (int b = 0; b < 4; ++b) {
        int j = j0 + tx + b * 16;
        S[(size_t)i * MM + j] = -acc4[a][b];
      }
    }

    // row partials: row i = i0 + ty + a*16, reduce over tx lanes + b
#pragma unroll
    for (int a = 0; a < 4; ++a) {
      float m = -acc4[a][0];
#pragma unroll
      for (int b = 1; b < 4; ++b) m = fmaxf(m, -acc4[a][b]);
      float s = 0.f;
#pragma unroll
      for (int b = 0; b < 4; ++b) s += __expf(-acc4[a][b] - m);
#pragma unroll
      for (int off = 1; off < 16; off <<= 1) {
        float m2 = __shfl_xor(m, off, 64);
        float s2 = __shfl_xor(s, off, 64);
        merge_ms(m, s, m2, s2);
      }
      if (tx == 0) {
        int i = i0 + ty + a * 16;
        rowPM[(size_t)jt * NN + i] = m;
        rowPS[(size_t)jt * NN + i] = s;
      }
    }

    // col partials stage 1: per-thread col reduction into lm/lsv
#pragma unroll
    for (int b = 0; b < 4; ++b) {
      int c = tx + b * 16;
      float m = -acc4[0][b];
#pragma unroll
      for (int a = 1; a < 4; ++a) m = fmaxf(m, -acc4[a][b]);
      float s = 0.f;
#pragma unroll
      for (int a = 0; a < 4; ++a) s += __expf(-acc4[a][b] - m);
      lm[ty][c] = m;
      lsv[ty][c] = s;
    }
  }
  __syncthreads();
  if (t < 64) {
    float m = lm[0][t], s = lsv[0][t];
#pragma unroll
    for (int k = 1; k < 16; ++k) merge_ms(m, s, lm[k][t], lsv[k][t]);
    colPM[(size_t)it * MM + j0 + t] = m;
    colPS[(size_t)it * MM + j0 + t] = s;
  }
}

// ---------------- K2: merge stats + weighted accumulation + final ----------
// 256 blocks x 4 rows (R6, measured ~4-6 us incl. gap).
__global__ __launch_bounds__(256) void k_wacc(const float* __restrict__ S,
                                              const float* __restrict__ rowPM,
                                              const float* __restrict__ rowPS,
                                              const float* __restrict__ colPM,
                                              const float* __restrict__ colPS,
                                              float* __restrict__ bNum,
                                              float* __restrict__ bDen,
                                              int* __restrict__ counter,
                                              float* __restrict__ out) {
  const int bid = blockIdx.x;  // rows [bid*4, bid*4+4)
  const int t = threadIdx.x;

  // col stats for cols 4t..4t+3 (registers; duplicated per block but parallel)
  float4 cm = reinterpret_cast<const float4*>(colPM)[t];
  float4 cs = reinterpret_cast<const float4*>(colPS)[t];
#pragma unroll
  for (int k = 1; k < NTB; ++k) {
    float4 m2 = reinterpret_cast<const float4*>(colPM + (size_t)k * MM)[t];
    float4 s2 = reinterpret_cast<const float4*>(colPS + (size_t)k * MM)[t];
    merge_ms(cm.x, cs.x, m2.x, s2.x);
    merge_ms(cm.y, cs.y, m2.y, s2.y);
    merge_ms(cm.z, cs.z, m2.z, s2.z);
    merge_ms(cm.w, cs.w, m2.w, s2.w);
  }
  float4 ci;
  ci.x = 1.f / cs.x; ci.y = 1.f / cs.y; ci.z = 1.f / cs.z; ci.w = 1.f / cs.w;

  // row stats for this block's 4 rows
  __shared__ float rowMl[4], rowIl[4];
  if (t < 4) {
    int r = bid * 4 + t;
    float m = rowPM[r], s = rowPS[r];
#pragma unroll
    for (int k = 1; k < NTB; ++k)
      merge_ms(m, s, rowPM[(size_t)k * NN + r], rowPS[(size_t)k * NN + r]);
    rowMl[t] = m;
    rowIl[t] = 1.f / s;
  }
  __syncthreads();

  // weighted accumulation over 4 rows x 1024 cols
  float num = 0.f, den = 0.f;
#pragma unroll
  for (int rl = 0; rl < 4; ++rl) {
    int row = bid * 4 + rl;
    float4 v = reinterpret_cast<const float4*>(S + (size_t)row * MM)[t];
    float rm = rowMl[rl], ri = rowIl[rl];
#define DO_COMP(VX, CMX, CIX)                 \
    {                                         \
      float a = __expf((VX) - rm) * ri;       \
      float b = __expf((VX) - (CMX)) * (CIX); \
      float w = a + b - a * b;                \
      num += w * (VX);                        \
      den += w;                               \
    }
    DO_COMP(v.x, cm.x, ci.x)
    DO_COMP(v.y, cm.y, ci.y)
    DO_COMP(v.z, cm.z, ci.z)
    DO_COMP(v.w, cm.w, ci.w)
#undef DO_COMP
  }

  // block reduce
  num = wredSum(num);
  den = wredSum(den);
  __shared__ float rn[4], rd[4];
  const int lane = t & 63, wv = t >> 6;
  if (lane == 0) { rn[wv] = num; rd[wv] = den; }
  __syncthreads();
  if (t == 0) {
    bNum[bid] = rn[0] + rn[1] + rn[2] + rn[3];
    bDen[bid] = rd[0] + rd[1] + rd[2] + rd[3];
  }

  // last-block-done final reduction (deterministic index-ordered sum)
  __shared__ int isLast;
  if (t == 0) {
    __threadfence();
    int ticket = atomicAdd(counter, 1);
    isLast = (ticket == 255) ? 1 : 0;
  }
  __syncthreads();
  if (isLast) {
    __threadfence();
    float n = bNum[t];
    float d = bDen[t];
    n = wredSum(n);
    d = wredSum(d);
    if (lane == 0) { rn[wv] = n; rd[wv] = d; }
    __syncthreads();
    if (t == 0) out[0] = (rn[0] + rn[1] + rn[2] + rn[3]) / (rd[0] + rd[1] + rd[2] + rd[3]);
  }
}

// ---------------- launch ----------------
extern "C" void kernel_launch(void* const* d_in, const int* in_sizes, int n_in,
                              void* d_out, int out_size, void* d_ws, size_t ws_size,
                              hipStream_t stream) {
  const float* zx = (const float*)d_in[0];
  const float* zy = (const float*)d_in[1];
  float* out = (float*)d_out;

  float* ws = (float*)d_ws;
  float* S     = ws;                        // 1M floats
  float* rowPM = S + (size_t)NN * MM;       // 16K
  float* rowPS = rowPM + NTB * NN;          // 16K
  float* colPM = rowPS + NTB * NN;          // 16K
  float* colPS = colPM + NTB * MM;          // 16K
  float* bNum  = colPS + NTB * MM;          // 256
  float* bDen  = bNum + 256;                // 256
  int*   counter = (int*)(bDen + 256);      // 1

  k_tile<<<dim3(NTB, NTB), 512, 0, stream>>>(zx, zy, S, rowPM, rowPS, colPM, colPS, counter);
  k_wacc<<<256, 256, 0, stream>>>(S, rowPM, rowPS, colPM, colPS, bNum, bDen, counter, out);
}

// Round 9
// 39.355 us; speedup vs baseline: 2.2913x; 1.0625x over previous
//
#include <hip/hip_runtime.h>
#include <math.h>
#include <string.h>

#define NN 1024
#define MM 1024
#define DD 256
#define TILE 64
#define NTB 16
#define PITCH_H 264  // f16 pitch: 264*2B=528B/row -> x-reads conflict-free, y-reads 2-way (free)

typedef _Float16 f16x2 __attribute__((ext_vector_type(2)));
typedef _Float16 f16x4 __attribute__((ext_vector_type(4)));

__device__ inline f16x2 habs2(f16x2 v) {
  unsigned u = __builtin_bit_cast(unsigned, v) & 0x7FFF7FFFu;
  return __builtin_bit_cast(f16x2, u);
}

__device__ inline float dot2acc(f16x2 a, float acc) {
#if __has_builtin(__builtin_amdgcn_fdot2)
  const f16x2 one = {(_Float16)1.0f, (_Float16)1.0f};
  return __builtin_amdgcn_fdot2(a, one, acc, false);
#else
  return acc + (float)a.x + (float)a.y;
#endif
}

__device__ inline void merge_ms(float& m, float& s, float m2, float s2) {
  float mn = fmaxf(m, m2);
  s = s * __expf(m - mn) + s2 * __expf(m2 - mn);
  m = mn;
}

__device__ inline float wredSum(float v) {
#pragma unroll
  for (int o = 32; o > 0; o >>= 1) v += __shfl_down(v, o, 64);
  return v;
}

// ---------------- K1: f16 distance tile + S store + row/col partials ----------
__global__ __launch_bounds__(256) void k_tile(const float* __restrict__ zx,
                                              const float* __restrict__ zy,
                                              float* __restrict__ S,
                                              float* __restrict__ rowPM,
                                              float* __restrict__ rowPS,
                                              float* __restrict__ colPM,
                                              float* __restrict__ colPS,
                                              int* __restrict__ counter) {
  __shared__ __align__(16) _Float16 xs[TILE * PITCH_H];  // 33 KiB
  __shared__ __align__(16) _Float16 ys[TILE * PITCH_H];  // 33 KiB
  __shared__ float lm[16][64];                           // 4 KiB
  __shared__ float lsv[16][64];                          // 4 KiB

  const int it = blockIdx.y, jt = blockIdx.x;
  const int i0 = it * TILE, j0 = jt * TILE;
  const int t = threadIdx.x;
  const int tx = t & 15, ty = t >> 4;

  if (it == 0 && jt == 0 && t == 0) counter[0] = 0;  // graph-replay-safe reset

  // stage 64 rows x 256 f32 of both inputs, converting to f16 (coalesced float4)
#pragma unroll
  for (int k = 0; k < 16; ++k) {
    int idx4 = t + k * 256;
    int r = idx4 >> 6;
    int c4 = idx4 & 63;
    float4 vx = reinterpret_cast<const float4*>(zx + (size_t)(i0 + r) * DD)[c4];
    float4 vy = reinterpret_cast<const float4*>(zy + (size_t)(j0 + r) * DD)[c4];
    f16x4 hx = {(_Float16)vx.x, (_Float16)vx.y, (_Float16)vx.z, (_Float16)vx.w};
    f16x4 hy = {(_Float16)vy.x, (_Float16)vy.y, (_Float16)vy.z, (_Float16)vy.w};
    *reinterpret_cast<f16x4*>(&xs[r * PITCH_H + c4 * 4]) = hx;
    *reinterpret_cast<f16x4*>(&ys[r * PITCH_H + c4 * 4]) = hy;
  }
  __syncthreads();

  // distance accumulation: 32 steps of 8 f16 elems; 1 ds_read_b128 per row per step
  float acc4[4][4] = {{0.f}};
  for (int s8 = 0; s8 < 32; ++s8) {
    uint4 xw[4], yw[4];
#pragma unroll
    for (int a = 0; a < 4; ++a)
      xw[a] = *reinterpret_cast<const uint4*>(&xs[(ty + a * 16) * PITCH_H + s8 * 8]);
#pragma unroll
    for (int b = 0; b < 4; ++b)
      yw[b] = *reinterpret_cast<const uint4*>(&ys[(tx + b * 16) * PITCH_H + s8 * 8]);
#pragma unroll
    for (int a = 0; a < 4; ++a)
#pragma unroll
      for (int b = 0; b < 4; ++b) {
        float acc = acc4[a][b];
        acc = dot2acc(habs2(__builtin_bit_cast(f16x2, xw[a].x) - __builtin_bit_cast(f16x2, yw[b].x)), acc);
        acc = dot2acc(habs2(__builtin_bit_cast(f16x2, xw[a].y) - __builtin_bit_cast(f16x2, yw[b].y)), acc);
        acc = dot2acc(habs2(__builtin_bit_cast(f16x2, xw[a].z) - __builtin_bit_cast(f16x2, yw[b].z)), acc);
        acc = dot2acc(habs2(__builtin_bit_cast(f16x2, xw[a].w) - __builtin_bit_cast(f16x2, yw[b].w)), acc);
        acc4[a][b] = acc;
      }
  }

  // store S tile (f32)
#pragma unroll
  for (int a = 0; a < 4; ++a) {
    int i = i0 + ty + a * 16;
#pragma unroll
    for (int b = 0; b < 4; ++b) {
      int j = j0 + tx + b * 16;
      S[(size_t)i * MM + j] = -acc4[a][b];
    }
  }

  // row partials: row i = i0 + ty + a*16, reduce over tx lanes + b
#pragma unroll
  for (int a = 0; a < 4; ++a) {
    float m = -acc4[a][0];
#pragma unroll
    for (int b = 1; b < 4; ++b) m = fmaxf(m, -acc4[a][b]);
    float s = 0.f;
#pragma unroll
    for (int b = 0; b < 4; ++b) s += __expf(-acc4[a][b] - m);
#pragma unroll
    for (int off = 1; off < 16; off <<= 1) {
      float m2 = __shfl_xor(m, off, 64);
      float s2 = __shfl_xor(s, off, 64);
      merge_ms(m, s, m2, s2);
    }
    if (tx == 0) {
      int i = i0 + ty + a * 16;
      rowPM[(size_t)jt * NN + i] = m;
      rowPS[(size_t)jt * NN + i] = s;
    }
  }

  // col partials: col c = tx + b*16, reduce over a regs + ty via LDS
#pragma unroll
  for (int b = 0; b < 4; ++b) {
    int c = tx + b * 16;
    float m = -acc4[0][b];
#pragma unroll
    for (int a = 1; a < 4; ++a) m = fmaxf(m, -acc4[a][b]);
    float s = 0.f;
#pragma unroll
    for (int a = 0; a < 4; ++a) s += __expf(-acc4[a][b] - m);
    lm[ty][c] = m;
    lsv[ty][c] = s;
  }
  __syncthreads();
  if (t < 64) {
    float m = lm[0][t], s = lsv[0][t];
#pragma unroll
    for (int k = 1; k < 16; ++k) merge_ms(m, s, lm[k][t], lsv[k][t]);
    colPM[(size_t)it * MM + j0 + t] = m;
    colPS[(size_t)it * MM + j0 + t] = s;
  }
}

// ---------------- K2: merge stats + weighted accumulation + final ----------
__global__ __launch_bounds__(256) void k_wacc(const float* __restrict__ S,
                                              const float* __restrict__ rowPM,
                                              const float* __restrict__ rowPS,
                                              const float* __restrict__ colPM,
                                              const float* __restrict__ colPS,
                                              float* __restrict__ bNum,
                                              float* __restrict__ bDen,
                                              int* __restrict__ counter,
                                              float* __restrict__ out) {
  const int bid = blockIdx.x;  // rows [bid*4, bid*4+4)
  const int t = threadIdx.x;

  // col stats for cols 4t..4t+3 (registers; duplicated per block but parallel)
  float4 cm = reinterpret_cast<const float4*>(colPM)[t];
  float4 cs = reinterpret_cast<const float4*>(colPS)[t];
#pragma unroll
  for (int k = 1; k < NTB; ++k) {
    float4 m2 = reinterpret_cast<const float4*>(colPM + (size_t)k * MM)[t];
    float4 s2 = reinterpret_cast<const float4*>(colPS + (size_t)k * MM)[t];
    merge_ms(cm.x, cs.x, m2.x, s2.x);
    merge_ms(cm.y, cs.y, m2.y, s2.y);
    merge_ms(cm.z, cs.z, m2.z, s2.z);
    merge_ms(cm.w, cs.w, m2.w, s2.w);
  }
  float4 ci;
  ci.x = 1.f / cs.x; ci.y = 1.f / cs.y; ci.z = 1.f / cs.z; ci.w = 1.f / cs.w;

  // row stats for this block's 4 rows
  __shared__ float rowMl[4], rowIl[4];
  if (t < 4) {
    int r = bid * 4 + t;
    float m = rowPM[r], s = rowPS[r];
#pragma unroll
    for (int k = 1; k < NTB; ++k)
      merge_ms(m, s, rowPM[(size_t)k * NN + r], rowPS[(size_t)k * NN + r]);
    rowMl[t] = m;
    rowIl[t] = 1.f / s;
  }
  __syncthreads();

  // weighted accumulation over 4 rows x 1024 cols
  float num = 0.f, den = 0.f;
#pragma unroll
  for (int rl = 0; rl < 4; ++rl) {
    int row = bid * 4 + rl;
    float4 v = reinterpret_cast<const float4*>(S + (size_t)row * MM)[t];
    float rm = rowMl[rl], ri = rowIl[rl];
#define DO_COMP(VX, CMX, CIX)                 \
    {                                         \
      float a = __expf((VX) - rm) * ri;       \
      float b = __expf((VX) - (CMX)) * (CIX); \
      float w = a + b - a * b;                \
      num += w * (VX);                        \
      den += w;                               \
    }
    DO_COMP(v.x, cm.x, ci.x)
    DO_COMP(v.y, cm.y, ci.y)
    DO_COMP(v.z, cm.z, ci.z)
    DO_COMP(v.w, cm.w, ci.w)
#undef DO_COMP
  }

  // block reduce
  num = wredSum(num);
  den = wredSum(den);
  __shared__ float rn[4], rd[4];
  const int lane = t & 63, wv = t >> 6;
  if (lane == 0) { rn[wv] = num; rd[wv] = den; }
  __syncthreads();
  if (t == 0) {
    bNum[bid] = rn[0] + rn[1] + rn[2] + rn[3];
    bDen[bid] = rd[0] + rd[1] + rd[2] + rd[3];
  }

  // last-block-done final reduction (deterministic index-ordered sum)
  __shared__ int isLast;
  if (t == 0) {
    __threadfence();
    int ticket = atomicAdd(counter, 1);
    isLast = (ticket == 255) ? 1 : 0;
  }
  __syncthreads();
  if (isLast) {
    __threadfence();
    float n = bNum[t];
    float d = bDen[t];
    n = wredSum(n);
    d = wredSum(d);
    if (lane == 0) { rn[wv] = n; rd[wv] = d; }
    __syncthreads();
    if (t == 0) out[0] = (rn[0] + rn[1] + rn[2] + rn[3]) / (rd[0] + rd[1] + rd[2] + rd[3]);
  }
}

// ---------------- launch ----------------
extern "C" void kernel_launch(void* const* d_in, const int* in_sizes, int n_in,
                              void* d_out, int out_size, void* d_ws, size_t ws_size,
                              hipStream_t stream) {
  const float* zx = (const float*)d_in[0];
  const float* zy = (const float*)d_in[1];
  float* out = (float*)d_out;

  float* ws = (float*)d_ws;
  float* S     = ws;                        // 1M floats
  float* rowPM = S + (size_t)NN * MM;       // 16K
  float* rowPS = rowPM + NTB * NN;          // 16K
  float* colPM = rowPS + NTB * NN;          // 16K
  float* colPS = colPM + NTB * MM;          // 16K
  float* bNum  = colPS + NTB * MM;          // 256
  float* bDen  = bNum + 256;                // 256
  int*   counter = (int*)(bDen + 256);      // 1

  k_tile<<<dim3(NTB, NTB), 256, 0, stream>>>(zx, zy, S, rowPM, rowPS, colPM, colPS, counter);
  k_wacc<<<256, 256, 0, stream>>>(S, rowPM, rowPS, colPM, colPS, bNum, bDen, counter, out);
}

// Round 10
// 32.301 us; speedup vs baseline: 2.7916x; 1.2184x over previous
//
#include <hip/hip_runtime.h>
#include <math.h>

#define NN 1024
#define MM 1024
#define DD 256
#define TI 32          // i-rows per block
#define TJ 64          // j-cols per block
#define NTI 32         // i-tiles (col-partial stripes)
#define NTJ 16         // j-tiles (row-partial stripes)
#define PITCH_H 264    // f16 pitch (528 B/row)

typedef _Float16 f16x2 __attribute__((ext_vector_type(2)));
typedef _Float16 f16x4 __attribute__((ext_vector_type(4)));

__device__ inline f16x2 habs2(f16x2 v) {
  unsigned u = __builtin_bit_cast(unsigned, v) & 0x7FFF7FFFu;
  return __builtin_bit_cast(f16x2, u);
}

__device__ inline float dot2acc(f16x2 a, float acc) {
#if __has_builtin(__builtin_amdgcn_fdot2)
  const f16x2 one = {(_Float16)1.0f, (_Float16)1.0f};
  return __builtin_amdgcn_fdot2(a, one, acc, false);
#else
  return acc + (float)a.x + (float)a.y;
#endif
}

__device__ inline void merge_ms(float& m, float& s, float m2, float s2) {
  float mn = fmaxf(m, m2);
  s = s * __expf(m - mn) + s2 * __expf(m2 - mn);
  m = mn;
}

__device__ inline float wredSum(float v) {
#pragma unroll
  for (int o = 32; o > 0; o >>= 1) v += __shfl_down(v, o, 64);
  return v;
}

// ---------------- K1: f16 distance, 32x64 tile, 512 blocks (2/CU) ----------
__global__ __launch_bounds__(256) void k_tile(const float* __restrict__ zx,
                                              const float* __restrict__ zy,
                                              float* __restrict__ S,
                                              float* __restrict__ rowPM,
                                              float* __restrict__ rowPS,
                                              float* __restrict__ colPM,
                                              float* __restrict__ colPS) {
  __shared__ __align__(16) _Float16 xs[TI * PITCH_H];  // 16.5 KiB
  __shared__ __align__(16) _Float16 ys[TJ * PITCH_H];  // 33 KiB
  __shared__ float lm[16][64];                         // 4 KiB
  __shared__ float lsv[16][64];                        // 4 KiB

  const int it = blockIdx.y, jt = blockIdx.x;   // it in [0,32), jt in [0,16)
  const int i0 = it * TI, j0 = jt * TJ;
  const int t = threadIdx.x;
  const int tx = t & 15, ty = t >> 4;

  // stage x: 32 rows x 256 f32 -> f16 (2048 float4, 8/thread, coalesced)
#pragma unroll
  for (int k = 0; k < 8; ++k) {
    int idx4 = t + k * 256;
    int r = idx4 >> 6;
    int c4 = idx4 & 63;
    float4 v = reinterpret_cast<const float4*>(zx + (size_t)(i0 + r) * DD)[c4];
    f16x4 h = {(_Float16)v.x, (_Float16)v.y, (_Float16)v.z, (_Float16)v.w};
    *reinterpret_cast<f16x4*>(&xs[r * PITCH_H + c4 * 4]) = h;
  }
  // stage y: 64 rows x 256 f32 -> f16 (4096 float4, 16/thread)
#pragma unroll
  for (int k = 0; k < 16; ++k) {
    int idx4 = t + k * 256;
    int r = idx4 >> 6;
    int c4 = idx4 & 63;
    float4 v = reinterpret_cast<const float4*>(zy + (size_t)(j0 + r) * DD)[c4];
    f16x4 h = {(_Float16)v.x, (_Float16)v.y, (_Float16)v.z, (_Float16)v.w};
    *reinterpret_cast<f16x4*>(&ys[r * PITCH_H + c4 * 4]) = h;
  }
  __syncthreads();

  // acc4[a][b]: rows i0+ty+a*16 (a<2), cols j0+tx+b*16 (b<4)
  float acc4[2][4] = {{0.f}};
  for (int s8 = 0; s8 < 32; ++s8) {
    uint4 xw[2], yw[4];
#pragma unroll
    for (int a = 0; a < 2; ++a)
      xw[a] = *reinterpret_cast<const uint4*>(&xs[(ty + a * 16) * PITCH_H + s8 * 8]);
#pragma unroll
    for (int b = 0; b < 4; ++b)
      yw[b] = *reinterpret_cast<const uint4*>(&ys[(tx + b * 16) * PITCH_H + s8 * 8]);
#pragma unroll
    for (int a = 0; a < 2; ++a)
#pragma unroll
      for (int b = 0; b < 4; ++b) {
        float acc = acc4[a][b];
        acc = dot2acc(habs2(__builtin_bit_cast(f16x2, xw[a].x) - __builtin_bit_cast(f16x2, yw[b].x)), acc);
        acc = dot2acc(habs2(__builtin_bit_cast(f16x2, xw[a].y) - __builtin_bit_cast(f16x2, yw[b].y)), acc);
        acc = dot2acc(habs2(__builtin_bit_cast(f16x2, xw[a].z) - __builtin_bit_cast(f16x2, yw[b].z)), acc);
        acc = dot2acc(habs2(__builtin_bit_cast(f16x2, xw[a].w) - __builtin_bit_cast(f16x2, yw[b].w)), acc);
        acc4[a][b] = acc;
      }
  }

  // store S tile (f32)
#pragma unroll
  for (int a = 0; a < 2; ++a) {
    int i = i0 + ty + a * 16;
#pragma unroll
    for (int b = 0; b < 4; ++b) {
      int j = j0 + tx + b * 16;
      S[(size_t)i * MM + j] = -acc4[a][b];
    }
  }

  // row partials: row i = i0+ty+a*16, reduce over b regs + tx lanes
#pragma unroll
  for (int a = 0; a < 2; ++a) {
    float m = -acc4[a][0];
#pragma unroll
    for (int b = 1; b < 4; ++b) m = fmaxf(m, -acc4[a][b]);
    float s = 0.f;
#pragma unroll
    for (int b = 0; b < 4; ++b) s += __expf(-acc4[a][b] - m);
#pragma unroll
    for (int off = 1; off < 16; off <<= 1) {
      float m2 = __shfl_xor(m, off, 64);
      float s2 = __shfl_xor(s, off, 64);
      merge_ms(m, s, m2, s2);
    }
    if (tx == 0) {
      int i = i0 + ty + a * 16;
      rowPM[(size_t)jt * NN + i] = m;
      rowPS[(size_t)jt * NN + i] = s;
    }
  }

  // col partials: col c = tx+b*16, reduce over a regs + ty via LDS
#pragma unroll
  for (int b = 0; b < 4; ++b) {
    int c = tx + b * 16;
    float m = fmaxf(-acc4[0][b], -acc4[1][b]);
    float s = __expf(-acc4[0][b] - m) + __expf(-acc4[1][b] - m);
    lm[ty][c] = m;
    lsv[ty][c] = s;
  }
  __syncthreads();
  if (t < 64) {
    float m = lm[0][t], s = lsv[0][t];
#pragma unroll
    for (int k = 1; k < 16; ++k) merge_ms(m, s, lm[k][t], lsv[k][t]);
    colPM[(size_t)it * MM + j0 + t] = m;
    colPS[(size_t)it * MM + j0 + t] = s;
  }
}

// ---------------- K2: merge stripe partials -> global stats (R4-proven) ----
__global__ __launch_bounds__(256) void k_merge(const float* __restrict__ rowPM,
                                               const float* __restrict__ rowPS,
                                               const float* __restrict__ colPM,
                                               const float* __restrict__ colPS,
                                               float* __restrict__ rowM,
                                               float* __restrict__ rowS,
                                               float* __restrict__ colM,
                                               float* __restrict__ colS) {
  int g = blockIdx.x * 256 + threadIdx.x;  // grid 8 -> g in [0, 2048)
  if (g < NN) {
    float m = rowPM[g], s = rowPS[g];
#pragma unroll
    for (int k = 1; k < NTJ; ++k)
      merge_ms(m, s, rowPM[(size_t)k * NN + g], rowPS[(size_t)k * NN + g]);
    rowM[g] = m;
    rowS[g] = s;
  } else {
    int c = g - NN;
    float m = colPM[c], s = colPS[c];
#pragma unroll
    for (int k = 1; k < NTI; ++k)
      merge_ms(m, s, colPM[(size_t)k * MM + c], colPS[(size_t)k * MM + c]);
    colM[c] = m;
    colS[c] = s;
  }
}

// ---------------- K3: weighted accumulation (R4-proven) ----------
__global__ __launch_bounds__(256) void k_accum(const float* __restrict__ S,
                                               const float* __restrict__ rowM,
                                               const float* __restrict__ rowS,
                                               const float* __restrict__ colM,
                                               const float* __restrict__ colS,
                                               float* __restrict__ bNum,
                                               float* __restrict__ bDen) {
  const int i = blockIdx.x;
  const int t = threadIdx.x;
  float4 v = reinterpret_cast<const float4*>(S + (size_t)i * MM)[t];
  const float rm = rowM[i];
  const float rinv = 1.f / rowS[i];
  float4 cm = reinterpret_cast<const float4*>(colM)[t];
  float4 cs = reinterpret_cast<const float4*>(colS)[t];
  float num = 0.f, den = 0.f;
#define DO_COMP(VX, CMX, CSX)               \
  {                                         \
    float a = __expf((VX) - rm) * rinv;     \
    float b = __expf((VX) - (CMX)) / (CSX); \
    float w = a + b - a * b;                \
    num += w * (VX);                        \
    den += w;                               \
  }
  DO_COMP(v.x, cm.x, cs.x)
  DO_COMP(v.y, cm.y, cs.y)
  DO_COMP(v.z, cm.z, cs.z)
  DO_COMP(v.w, cm.w, cs.w)
#undef DO_COMP
  num = wredSum(num);
  den = wredSum(den);
  __shared__ float rn[4], rd[4];
  const int lane = t & 63, wv = t >> 6;
  if (lane == 0) { rn[wv] = num; rd[wv] = den; }
  __syncthreads();
  if (t == 0) {
    bNum[i] = rn[0] + rn[1] + rn[2] + rn[3];
    bDen[i] = rd[0] + rd[1] + rd[2] + rd[3];
  }
}

// ---------------- K4: final reduce + divide (R4-proven) ----------------
__global__ __launch_bounds__(256) void k_final(const float* __restrict__ bNum,
                                               const float* __restrict__ bDen,
                                               float* __restrict__ out) {
  const int t = threadIdx.x;
  float4 n4 = reinterpret_cast<const float4*>(bNum)[t];
  float4 d4 = reinterpret_cast<const float4*>(bDen)[t];
  float n = n4.x + n4.y + n4.z + n4.w;
  float d = d4.x + d4.y + d4.z + d4.w;
  n = wredSum(n);
  d = wredSum(d);
  __shared__ float rn[4], rd[4];
  const int lane = t & 63, wv = t >> 6;
  if (lane == 0) { rn[wv] = n; rd[wv] = d; }
  __syncthreads();
  if (t == 0) out[0] = (rn[0] + rn[1] + rn[2] + rn[3]) / (rd[0] + rd[1] + rd[2] + rd[3]);
}

// ---------------- launch ----------------
extern "C" void kernel_launch(void* const* d_in, const int* in_sizes, int n_in,
                              void* d_out, int out_size, void* d_ws, size_t ws_size,
                              hipStream_t stream) {
  const float* zx = (const float*)d_in[0];
  const float* zy = (const float*)d_in[1];
  float* out = (float*)d_out;

  float* ws = (float*)d_ws;
  float* S     = ws;                        // 1M floats
  float* rowPM = S + (size_t)NN * MM;       // 16K  (NTJ x NN)
  float* rowPS = rowPM + NTJ * NN;          // 16K
  float* colPM = rowPS + NTJ * NN;          // 32K  (NTI x MM)
  float* colPS = colPM + NTI * MM;          // 32K
  float* rowM  = colPS + NTI * MM;          // 1K
  float* rowS  = rowM + NN;                 // 1K
  float* colM  = rowS + NN;                 // 1K
  float* colS  = colM + MM;                 // 1K
  float* bNum  = colS + MM;                 // 1K
  float* bDen  = bNum + NN;                 // 1K

  k_tile<<<dim3(NTJ, NTI), 256, 0, stream>>>(zx, zy, S, rowPM, rowPS, colPM, colPS);
  k_merge<<<8, 256, 0, stream>>>(rowPM, rowPS, colPM, colPS, rowM, rowS, colM, colS);
  k_accum<<<NN, 256, 0, stream>>>(S, rowM, rowS, colM, colS, bNum, bDen);
  k_final<<<1, 256, 0, stream>>>(bNum, bDen, out);
}